// Round 2
// baseline (690.511 us; speedup 1.0000x reference)
//
#include <hip/hip_runtime.h>

// Problem constants (fixed by setup_inputs)
#define Bsz 4
#define Cc  512
#define C2  1024
#define H0c 192
#define Hh  48
#define Nn  2304   // 48*48
#define HNh 8
#define HD  64
#define Hs  25
#define Ms  625    // 25*25

typedef const float* fp;
typedef _Float16 f16;
typedef __attribute__((ext_vector_type(8))) _Float16 f16x8;
typedef __attribute__((ext_vector_type(4))) _Float16 f16x4;
typedef __attribute__((ext_vector_type(4))) float    f32x4;

// ---------------- K1: fused stride-4 nearest downsample + transpose ----------------
// x f32 [b][512][192][192] -> xds f32 [b][512][2304] (for sr1), xt f16 [b][2304][512]
__global__ __launch_bounds__(256) void k_ds_t(fp __restrict__ x,
                                              float* __restrict__ xds,
                                              f16* __restrict__ xt) {
    __shared__ float tile[32][33];
    const int b = blockIdx.z;
    const int s0 = blockIdx.x * 32, r0 = blockIdx.y * 32;   // s: n (2304), r: c (512)
    const int t = threadIdx.x;
    const float* xb = x + (size_t)b * Cc * H0c * H0c;
    float* xdsb = xds + (size_t)b * Cc * Nn;
    #pragma unroll
    for (int p = 0; p < 4; p++) {
        int e = t + p * 256; int i = e >> 5, j = e & 31;
        int c = r0 + i, n = s0 + j;
        float v = xb[((size_t)c * H0c + (n / Hh) * 4) * H0c + (n % Hh) * 4];
        tile[i][j] = v;
        xdsb[(size_t)c * Nn + n] = v;
    }
    __syncthreads();
    #pragma unroll
    for (int p = 0; p < 4; p++) {
        int e = t + p * 256; int oi = e >> 5, oj = e & 31;
        xt[((size_t)b * Nn + s0 + oi) * Cc + r0 + oj] = (f16)tile[oj][oi];
    }
}

// ---------------- K2: fused 2x2 dwconv s2 p1 + BN + ReLU + transpose ----------------
// xds f32 [b][512][2304] -> kv1t f16 [b][625][512] (k-contig rows for GEMM B)
__global__ __launch_bounds__(256) void k_sr1t(const float* __restrict__ xds,
                                              fp __restrict__ w, fp g, fp bb, fp bm, fp bv,
                                              f16* __restrict__ kv1t) {
    __shared__ float tile[32][33];
    const int b = blockIdx.z;
    const int s0 = blockIdx.x * 32, r0 = blockIdx.y * 32;   // s: n (625), r: c (512)
    const int t = threadIdx.x;
    #pragma unroll
    for (int p = 0; p < 4; p++) {
        int e = t + p * 256; int i = e >> 5, j = e & 31;
        int c = r0 + i, n = s0 + j;
        float v = 0.f;
        if (n < Ms) {
            int ho = n / Hs, wo = n % Hs;
            const float* src = xds + ((size_t)b * Cc + c) * Nn;
            float acc = 0.f;
            #pragma unroll
            for (int di = 0; di < 2; di++) {
                int ih = ho * 2 - 1 + di;
                if (ih < 0 || ih >= Hh) continue;
                #pragma unroll
                for (int dj = 0; dj < 2; dj++) {
                    int iw = wo * 2 - 1 + dj;
                    if (iw < 0 || iw >= Hh) continue;
                    acc += w[c * 4 + di * 2 + dj] * src[ih * Hh + iw];
                }
            }
            float sc = g[c] * rsqrtf(bv[c] + 1e-5f);
            v = fmaxf((acc - bm[c]) * sc + bb[c], 0.f);
        }
        tile[i][j] = v;
    }
    __syncthreads();
    #pragma unroll
    for (int p = 0; p < 4; p++) {
        int e = t + p * 256; int oi = e >> 5, oj = e & 31;
        if (s0 + oi < Ms)
            kv1t[((size_t)b * Ms + s0 + oi) * Cc + r0 + oj] = (f16)tile[oj][oi];
    }
}

// ---------------- K4: fused 3x3 dwconv s1 p1 + bias + residual + transpose ----------------
// kv2 f32 [b][512][625] -> kv3t f16 [b][625][512]
__global__ __launch_bounds__(256) void k_lct(const float* __restrict__ kv2,
                                             fp __restrict__ w, fp __restrict__ lb,
                                             f16* __restrict__ kv3t) {
    __shared__ float tile[32][33];
    const int b = blockIdx.z;
    const int s0 = blockIdx.x * 32, r0 = blockIdx.y * 32;   // s: n (625), r: c (512)
    const int t = threadIdx.x;
    #pragma unroll
    for (int p = 0; p < 4; p++) {
        int e = t + p * 256; int i = e >> 5, j = e & 31;
        int c = r0 + i, n = s0 + j;
        float v = 0.f;
        if (n < Ms) {
            int ho = n / Hs, wo = n % Hs;
            const float* src = kv2 + ((size_t)b * Cc + c) * Ms;
            float acc = 0.f;
            #pragma unroll
            for (int di = 0; di < 3; di++) {
                int ih = ho - 1 + di;
                if (ih < 0 || ih >= Hs) continue;
                #pragma unroll
                for (int dj = 0; dj < 3; dj++) {
                    int iw = wo - 1 + dj;
                    if (iw < 0 || iw >= Hs) continue;
                    acc += w[c * 9 + di * 3 + dj] * src[ih * Hs + iw];
                }
            }
            v = acc + lb[c] + src[n];
        }
        tile[i][j] = v;
    }
    __syncthreads();
    #pragma unroll
    for (int p = 0; p < 4; p++) {
        int e = t + p * 256; int oi = e >> 5, oj = e & 31;
        if (s0 + oi < Ms)
            kv3t[((size_t)b * Ms + s0 + oi) * Cc + r0 + oj] = (f16)tile[oj][oi];
    }
}

// ---------------- MFMA GEMM: Y[b][o][n] = sum_c W[o][c] * Xt[b][n][c] ----------------
// W f32 [Md][512] (k-contig). Xt f16 [b][Nd][512] (k-contig rows).
// mode 0: Yf f32 [b][Md][Nd], epilogue (bias?, BN?)
// mode 1: Yt f16 [(b*8+h)][NtRows][64] per-head transposed (+bias)
// mode 2: o<512 -> mode1 path into Yt (Kt); o>=512 -> Vt f16 [b*512+o'][640], cols>=625 zero
__global__ __launch_bounds__(256) void k_gemm_mfma(
    const float* __restrict__ W, const f16* __restrict__ Xt,
    float* __restrict__ Yf, f16* __restrict__ Yt, f16* __restrict__ Vt,
    const int Md, const int Nd, const int NtRows, const int mode,
    fp __restrict__ bias,
    fp __restrict__ bn_g, fp __restrict__ bn_b, fp __restrict__ bn_m, fp __restrict__ bn_v)
{
    __shared__ f16 sA[128 * 80];   // [m][k], stride 80 (160B rows: 16B-aligned, bank-balanced)
    __shared__ f16 sB[128 * 80];   // [n][k]
    const int b  = blockIdx.z;
    const int m0 = blockIdx.y * 128, n0 = blockIdx.x * 128;
    const int t = threadIdx.x;
    const int lane = t & 63, w = t >> 6;
    const int lm = lane & 15, q = lane >> 4;
    const int wm = w >> 1, wn = w & 1;
    const f16* Xb = Xt + (size_t)b * Nd * 512;

    f32x4 acc[4][4];
    #pragma unroll
    for (int i = 0; i < 4; i++)
        #pragma unroll
        for (int j = 0; j < 4; j++)
            #pragma unroll
            for (int r = 0; r < 4; r++) acc[i][j][r] = 0.f;

    for (int k0 = 0; k0 < 512; k0 += 64) {
        {   // stage A (W f32 -> f16), 128 rows x 64 k
            int r = t >> 1, hh = (t & 1) * 32;
            const float* wr = W + (size_t)(m0 + r) * 512 + k0 + hh;
            f16* dst = &sA[r * 80 + hh];
            #pragma unroll
            for (int i = 0; i < 8; i++) {
                float4 v = *(const float4*)&wr[i * 4];
                f16x4 h4; h4[0] = (f16)v.x; h4[1] = (f16)v.y; h4[2] = (f16)v.z; h4[3] = (f16)v.w;
                *(f16x4*)&dst[i * 4] = h4;
            }
        }
        {   // stage B (Xt f16), 128 n-rows x 64 k
            int r = t >> 1, hh = (t & 1) * 32;
            bool ok = (n0 + r) < Nd;
            const f16* xr = Xb + (size_t)(n0 + r) * 512 + k0 + hh;
            f16* dst = &sB[r * 80 + hh];
            #pragma unroll
            for (int i = 0; i < 4; i++) {
                f16x8 v;
                if (ok) {
                    v = *(const f16x8*)&xr[i * 8];
                } else {
                    for (int z = 0; z < 8; z++) v[z] = (f16)0.f;
                }
                *(f16x8*)&dst[i * 8] = v;
            }
        }
        __syncthreads();
        #pragma unroll
        for (int ks = 0; ks < 2; ks++) {
            f16x8 af[4], bf[4];
            #pragma unroll
            for (int i = 0; i < 4; i++)
                af[i] = *(const f16x8*)&sA[(wm * 64 + i * 16 + lm) * 80 + ks * 32 + q * 8];
            #pragma unroll
            for (int j = 0; j < 4; j++)
                bf[j] = *(const f16x8*)&sB[(wn * 64 + j * 16 + lm) * 80 + ks * 32 + q * 8];
            #pragma unroll
            for (int i = 0; i < 4; i++)
                #pragma unroll
                for (int j = 0; j < 4; j++)
                    acc[i][j] = __builtin_amdgcn_mfma_f32_16x16x32_f16(af[i], bf[j], acc[i][j], 0, 0, 0);
        }
        __syncthreads();
    }

    // epilogue: D layout col=lane&15 (n), row=q*4+reg (o)
    #pragma unroll
    for (int i = 0; i < 4; i++) {
        int ob = m0 + wm * 64 + i * 16 + q * 4;       // + reg
        float badd[4], bsc[4], bsh[4];
        #pragma unroll
        for (int r = 0; r < 4; r++) {
            int o = ob + r;
            badd[r] = bias ? bias[o] : 0.f;
            if (bn_g) { bsc[r] = bn_g[o] * rsqrtf(bn_v[o] + 1e-5f); bsh[r] = bn_b[o] - bn_m[o] * bsc[r]; }
            else      { bsc[r] = 1.f; bsh[r] = 0.f; }
        }
        #pragma unroll
        for (int j = 0; j < 4; j++) {
            int n = n0 + wn * 64 + j * 16 + lm;
            f32x4 a = acc[i][j];
            if (mode == 0) {
                if (n < Nd) {
                    #pragma unroll
                    for (int r = 0; r < 4; r++)
                        Yf[((size_t)b * Md + ob + r) * Nd + n] = (a[r] + badd[r]) * bsc[r] + bsh[r];
                }
            } else if (mode == 1 || (mode == 2 && ob < 512)) {
                // n < NtRows always (grid exact); rows >= 625 in mode 2 hold finite
                // bias-only values and are masked post-multiply in attention.
                f16x4 h;
                #pragma unroll
                for (int r = 0; r < 4; r++) h[r] = (f16)(a[r] + badd[r]);
                int hh = ob >> 6, d0 = ob & 63;
                *(f16x4*)&Yt[((size_t)(b * 8 + hh) * NtRows + n) * 64 + d0] = h;
            } else { // mode 2, v-half -> Vt f16 [b*512 + o'][640], zero-pad cols >= 625
                #pragma unroll
                for (int r = 0; r < 4; r++) {
                    float val = (n < Nd) ? (a[r] + badd[r]) : 0.f;
                    Vt[((size_t)b * Cc + (ob + r - 512)) * 640 + n] = (f16)val;
                }
            }
        }
    }
}

// ---------------- MFMA flash attention + fused 4x nearest upsample ----------------
// Qt f16 [bh][2304][64]; Kt f16 [bh][640][64] (rows>=625 finite, masked);
// Vt f16 [bh*64 + d][640] (cols>=625 zero)  ->  out f32 [b][512][192][192]
__global__ __launch_bounds__(256) void k_attn_mfma(
    const f16* __restrict__ Qt, const f16* __restrict__ Kt,
    const f16* __restrict__ Vt, float* __restrict__ out)
{
    __shared__ f16 sK[64 * 80];       // [key][d]
    __shared__ f16 sV[64 * 80];       // [d][key]
    __shared__ f16 sP[4][16 * 80];    // per-wave [qrow][key]

    int bh = blockIdx.y;
    int n0 = blockIdx.x * 64;
    int t = threadIdx.x, w = t >> 6, lane = t & 63;
    int lm = lane & 15, q = lane >> 4;
    f16* sPw = &sP[w][0];

    // Q fragments (held in registers across all chunks)
    f16x8 qf[2];
    {
        const f16* qrow = Qt + ((size_t)bh * Nn + n0 + w * 16 + lm) * 64;
        qf[0] = *(const f16x8*)&qrow[q * 8];
        qf[1] = *(const f16x8*)&qrow[32 + q * 8];
    }

    f32x4 od[4];
    #pragma unroll
    for (int dt = 0; dt < 4; dt++)
        #pragma unroll
        for (int r = 0; r < 4; r++) od[dt][r] = 0.f;
    float mold[4], lold[4];
    #pragma unroll
    for (int r = 0; r < 4; r++) { mold[r] = -1e30f; lold[r] = 0.f; }

    int kr = t >> 2, kc = t & 3;
    const f16* kbase = Kt + (size_t)bh * 640 * 64;
    const f16* vbase = Vt + (size_t)bh * 64 * 640;

    for (int mc = 0; mc < 640; mc += 64) {
        {   // stage K [key][d] and V [d][key]
            const f16* ksrc = kbase + (size_t)(mc + kr) * 64;
            *(f16x8*)&sK[kr * 80 + kc * 8]      = *(const f16x8*)&ksrc[kc * 8];
            *(f16x8*)&sK[kr * 80 + 32 + kc * 8] = *(const f16x8*)&ksrc[32 + kc * 8];
            const f16* vsrc = vbase + (size_t)kr * 640 + mc;
            *(f16x8*)&sV[kr * 80 + kc * 8]      = *(const f16x8*)&vsrc[kc * 8];
            *(f16x8*)&sV[kr * 80 + 32 + kc * 8] = *(const f16x8*)&vsrc[32 + kc * 8];
        }
        __syncthreads();

        // scores S = Q K^T : A=Q[qrow][d], B=K^T[d][key]
        f32x4 sc4[4];
        #pragma unroll
        for (int j = 0; j < 4; j++)
            #pragma unroll
            for (int r = 0; r < 4; r++) sc4[j][r] = 0.f;
        #pragma unroll
        for (int ks = 0; ks < 2; ks++) {
            #pragma unroll
            for (int j = 0; j < 4; j++) {
                f16x8 kf = *(const f16x8*)&sK[(j * 16 + lm) * 80 + ks * 32 + q * 8];
                sc4[j] = __builtin_amdgcn_mfma_f32_16x16x32_f16(qf[ks], kf, sc4[j], 0, 0, 0);
            }
        }

        // online softmax; row r = q*4+reg, cols j*16+lm
        #pragma unroll
        for (int reg = 0; reg < 4; reg++) {
            float mx = -1e30f;
            #pragma unroll
            for (int j = 0; j < 4; j++) {
                float s = sc4[j][reg] * 0.125f;
                if (mc + j * 16 + lm >= Ms) s = -1e30f;
                sc4[j][reg] = s;
                mx = fmaxf(mx, s);
            }
            #pragma unroll
            for (int off = 1; off < 16; off <<= 1) mx = fmaxf(mx, __shfl_xor(mx, off));
            float mnew = fmaxf(mold[reg], mx);
            float alpha = __expf(mold[reg] - mnew);
            float rs = 0.f;
            #pragma unroll
            for (int j = 0; j < 4; j++) {
                float p = __expf(sc4[j][reg] - mnew);
                sc4[j][reg] = p;
                rs += p;
            }
            #pragma unroll
            for (int off = 1; off < 16; off <<= 1) rs += __shfl_xor(rs, off);
            lold[reg] = lold[reg] * alpha + rs;
            mold[reg] = mnew;
            #pragma unroll
            for (int dt = 0; dt < 4; dt++) od[dt][reg] *= alpha;
            #pragma unroll
            for (int j = 0; j < 4; j++)
                sPw[(q * 4 + reg) * 80 + j * 16 + lm] = (f16)sc4[j][reg];
        }

        // O += P V : A=P[qrow][key], B=V^T[key][d] (sV holds [d][key])
        #pragma unroll
        for (int ks = 0; ks < 2; ks++) {
            f16x8 pa = *(const f16x8*)&sPw[lm * 80 + ks * 32 + q * 8];
            #pragma unroll
            for (int dt = 0; dt < 4; dt++) {
                f16x8 vf = *(const f16x8*)&sV[(dt * 16 + lm) * 80 + ks * 32 + q * 8];
                od[dt] = __builtin_amdgcn_mfma_f32_16x16x32_f16(pa, vf, od[dt], 0, 0, 0);
            }
        }
        __syncthreads();
    }

    // epilogue: normalize + fused 4x4 nearest upsample store.
    // od[dt]: col=lm -> d (= dt*16+lm), row=q*4+reg -> qrow; n = n0 + w*16 + q*4 + reg.
    // n is a multiple of 4 at reg=0 and n%48 <= 44, so the 4 regs stay in one output row band.
    float inv4[4];
    #pragma unroll
    for (int r = 0; r < 4; r++) inv4[r] = 1.f / lold[r];
    const int bq = bh >> 3, hch = (bh & 7) * 64;
    const int nq = n0 + w * 16 + q * 4;
    const int i4 = (nq / Hh) * 4, j4 = (nq % Hh) * 4;
    #pragma unroll
    for (int dt = 0; dt < 4; dt++) {
        float* oc = out + ((size_t)(bq * Cc + hch + dt * 16 + lm) * H0c + i4) * H0c + j4;
        #pragma unroll
        for (int r = 0; r < 4; r++) {
            float val = od[dt][r] * inv4[r];
            float4 pk = make_float4(val, val, val, val);
            #pragma unroll
            for (int ii = 0; ii < 4; ii++)
                *(float4*)&oc[ii * H0c + r * 4] = pk;
        }
    }
}

extern "C" void kernel_launch(void* const* d_in, const int* in_sizes, int n_in,
                              void* d_out, int out_size, void* d_ws, size_t ws_size,
                              hipStream_t stream) {
    (void)in_sizes; (void)n_in; (void)out_size; (void)ws_size;
    fp x     = (fp)d_in[0];
    fp q_w   = (fp)d_in[1];
    fp q_b   = (fp)d_in[2];
    fp kv_w  = (fp)d_in[3];
    fp kv_b  = (fp)d_in[4];
    fp sr1_w = (fp)d_in[5];
    fp bn1_g = (fp)d_in[6];
    fp bn1_b = (fp)d_in[7];
    fp bn1_m = (fp)d_in[8];
    fp bn1_v = (fp)d_in[9];
    fp sr2_w = (fp)d_in[10];
    fp bn2_g = (fp)d_in[11];
    fp bn2_b = (fp)d_in[12];
    fp bn2_m = (fp)d_in[13];
    fp bn2_v = (fp)d_in[14];
    fp lc_w  = (fp)d_in[15];
    fp lc_b  = (fp)d_in[16];
    float* out = (float*)d_out;

    // workspace layout (f32 slots), peak 9,437,184 f32 = 37.7 MB
    // lifetimes: xds [k1..k3) | xt [k1..k2) | Qt [k2..k7] | kv1t [k3..k4) |
    //            kv2 [k4..k5) | kv3t [k5..k6) | Kt,vt [k6..k7]
    float* ws   = (float*)d_ws;
    float* xds  = ws;                          // [0, 4718592) f32
    float* kv2  = ws;                          // [0, 1280000) alias (xds dead after k_sr1t)
    f16*   Kt   = (f16*)(ws + 1310720);        // [1310720, 1966080) = 1,310,720 f16
    f16*   vt   = (f16*)(ws + 1966080);        // [1966080, 2621440) = 1,310,720 f16
    f16*   xt   = (f16*)(ws + 4718592);        // [4718592, 7077888) = 4,718,592 f16
    f16*   kv1t = (f16*)(ws + 4718592);        // alias xt (xt dead after q-gemm)
    f16*   kv3t = (f16*)(ws + 5358592);        // [5358592, 5998592) = 1,280,000 f16
    f16*   Qt   = (f16*)(ws + 7077888);        // [7077888, 9437184) = 4,718,592 f16

    // 1. downsample + transpose
    k_ds_t<<<dim3(72, 16, Bsz), 256, 0, stream>>>(x, xds, xt);
    // 2. q projection -> Qt (per-head f16)
    k_gemm_mfma<<<dim3(18, 4, Bsz), 256, 0, stream>>>(q_w, xt, nullptr, Qt, nullptr,
        Cc, Nn, Nn, 1, q_b, nullptr, nullptr, nullptr, nullptr);
    // 3. sr1 (2x2 dw s2 + BN + ReLU) + transpose
    k_sr1t<<<dim3(20, 16, Bsz), 256, 0, stream>>>(xds, sr1_w, bn1_g, bn1_b, bn1_m, bn1_v, kv1t);
    // 4. sr2 1x1 + BN -> kv2 f32
    k_gemm_mfma<<<dim3(5, 4, Bsz), 256, 0, stream>>>(sr2_w, kv1t, kv2, nullptr, nullptr,
        Cc, Ms, 0, 0, nullptr, bn2_g, bn2_b, bn2_m, bn2_v);
    // 5. lc (3x3 dw + bias + residual) + transpose
    k_lct<<<dim3(20, 16, Bsz), 256, 0, stream>>>(kv2, lc_w, lc_b, kv3t);
    // 6. kv projection -> Kt (per-head f16) + vt (f16, zero-padded cols)
    k_gemm_mfma<<<dim3(5, 8, Bsz), 256, 0, stream>>>(kv_w, kv3t, nullptr, Kt, vt,
        C2, Ms, 640, 2, kv_b, nullptr, nullptr, nullptr, nullptr);
    // 7. attention + fused 4x upsample -> out
    k_attn_mfma<<<dim3(Nn / 64, Bsz * HNh), 256, 0, stream>>>(Qt, Kt, vt, out);
}

// Round 3
// 617.189 us; speedup vs baseline: 1.1188x; 1.1188x over previous
//
#include <hip/hip_runtime.h>

// Problem constants (fixed by setup_inputs)
#define Bsz 4
#define Cc  512
#define C2  1024
#define H0c 192
#define Hh  48
#define Nn  2304   // 48*48
#define HNh 8
#define HD  64
#define Hs  25
#define Ms  625    // 25*25

typedef const float* fp;
typedef _Float16 f16;
typedef __attribute__((ext_vector_type(8))) _Float16 f16x8;
typedef __attribute__((ext_vector_type(4))) _Float16 f16x4;
typedef __attribute__((ext_vector_type(4))) float    f32x4;

// ---------------- K0: one-shot weight f32->f16 conversion ----------------
// wh layout: [q_w 262144][sr2_w 262144][kv_w 524288]  (1,048,576 f16 total)
__global__ __launch_bounds__(256) void k_cvtw(fp __restrict__ q_w, fp __restrict__ sr2_w,
                                              fp __restrict__ kv_w, f16* __restrict__ wh) {
    int idx = blockIdx.x * 256 + threadIdx.x;      // < 1048576
    float v;
    if (idx < 262144)      v = q_w[idx];
    else if (idx < 524288) v = sr2_w[idx - 262144];
    else                   v = kv_w[idx - 524288];
    wh[idx] = (f16)v;
}

// ---------------- K1: fused stride-4 nearest downsample + transpose ----------------
// x f32 [b][512][192][192] -> xds f32 [b][512][2304] (for sr1), xt f16 [b][2304][512]
__global__ __launch_bounds__(256) void k_ds_t(fp __restrict__ x,
                                              float* __restrict__ xds,
                                              f16* __restrict__ xt) {
    __shared__ float tile[32][33];
    const int b = blockIdx.z;
    const int s0 = blockIdx.x * 32, r0 = blockIdx.y * 32;   // s: n (2304), r: c (512)
    const int t = threadIdx.x;
    const float* xb = x + (size_t)b * Cc * H0c * H0c;
    float* xdsb = xds + (size_t)b * Cc * Nn;
    #pragma unroll
    for (int p = 0; p < 4; p++) {
        int e = t + p * 256; int i = e >> 5, j = e & 31;
        int c = r0 + i, n = s0 + j;
        float v = xb[((size_t)c * H0c + (n / Hh) * 4) * H0c + (n % Hh) * 4];
        tile[i][j] = v;
        xdsb[(size_t)c * Nn + n] = v;
    }
    __syncthreads();
    #pragma unroll
    for (int p = 0; p < 4; p++) {
        int e = t + p * 256; int oi = e >> 5, oj = e & 31;
        xt[((size_t)b * Nn + s0 + oi) * Cc + r0 + oj] = (f16)tile[oj][oi];
    }
}

// ---------------- K2: fused 2x2 dwconv s2 p1 + BN + ReLU + transpose ----------------
// xds f32 [b][512][2304] -> kv1t f16 [b][625][512] (k-contig rows for GEMM B)
__global__ __launch_bounds__(256) void k_sr1t(const float* __restrict__ xds,
                                              fp __restrict__ w, fp g, fp bb, fp bm, fp bv,
                                              f16* __restrict__ kv1t) {
    __shared__ float tile[32][33];
    const int b = blockIdx.z;
    const int s0 = blockIdx.x * 32, r0 = blockIdx.y * 32;   // s: n (625), r: c (512)
    const int t = threadIdx.x;
    #pragma unroll
    for (int p = 0; p < 4; p++) {
        int e = t + p * 256; int i = e >> 5, j = e & 31;
        int c = r0 + i, n = s0 + j;
        float v = 0.f;
        if (n < Ms) {
            int ho = n / Hs, wo = n % Hs;
            const float* src = xds + ((size_t)b * Cc + c) * Nn;
            float acc = 0.f;
            #pragma unroll
            for (int di = 0; di < 2; di++) {
                int ih = ho * 2 - 1 + di;
                if (ih < 0 || ih >= Hh) continue;
                #pragma unroll
                for (int dj = 0; dj < 2; dj++) {
                    int iw = wo * 2 - 1 + dj;
                    if (iw < 0 || iw >= Hh) continue;
                    acc += w[c * 4 + di * 2 + dj] * src[ih * Hh + iw];
                }
            }
            float sc = g[c] * rsqrtf(bv[c] + 1e-5f);
            v = fmaxf((acc - bm[c]) * sc + bb[c], 0.f);
        }
        tile[i][j] = v;
    }
    __syncthreads();
    #pragma unroll
    for (int p = 0; p < 4; p++) {
        int e = t + p * 256; int oi = e >> 5, oj = e & 31;
        if (s0 + oi < Ms)
            kv1t[((size_t)b * Ms + s0 + oi) * Cc + r0 + oj] = (f16)tile[oj][oi];
    }
}

// ---------------- K4: fused 3x3 dwconv s1 p1 + bias + residual + transpose ----------------
// kv2 f32 [b][512][625] -> kv3t f16 [b][625][512]
__global__ __launch_bounds__(256) void k_lct(const float* __restrict__ kv2,
                                             fp __restrict__ w, fp __restrict__ lb,
                                             f16* __restrict__ kv3t) {
    __shared__ float tile[32][33];
    const int b = blockIdx.z;
    const int s0 = blockIdx.x * 32, r0 = blockIdx.y * 32;   // s: n (625), r: c (512)
    const int t = threadIdx.x;
    #pragma unroll
    for (int p = 0; p < 4; p++) {
        int e = t + p * 256; int i = e >> 5, j = e & 31;
        int c = r0 + i, n = s0 + j;
        float v = 0.f;
        if (n < Ms) {
            int ho = n / Hs, wo = n % Hs;
            const float* src = kv2 + ((size_t)b * Cc + c) * Ms;
            float acc = 0.f;
            #pragma unroll
            for (int di = 0; di < 3; di++) {
                int ih = ho - 1 + di;
                if (ih < 0 || ih >= Hs) continue;
                #pragma unroll
                for (int dj = 0; dj < 3; dj++) {
                    int iw = wo - 1 + dj;
                    if (iw < 0 || iw >= Hs) continue;
                    acc += w[c * 9 + di * 3 + dj] * src[ih * Hs + iw];
                }
            }
            v = acc + lb[c] + src[n];
        }
        tile[i][j] = v;
    }
    __syncthreads();
    #pragma unroll
    for (int p = 0; p < 4; p++) {
        int e = t + p * 256; int oi = e >> 5, oj = e & 31;
        if (s0 + oi < Ms)
            kv3t[((size_t)b * Ms + s0 + oi) * Cc + r0 + oj] = (f16)tile[oj][oi];
    }
}

// ---------------- MFMA GEMM: Y[b][o][n] = sum_c W[o][c] * Xt[b][n][c] ----------------
// W f16 [Md][512] (k-contig, pre-converted). Xt f16 [b][Nd][512].
// mode 0: Yf f32 [b][Md][Nd], epilogue (bias?, BN?)
// mode 1: Yt f16 [(b*8+h)][NtRows][64] per-head transposed (+bias, *oscale)
// mode 2: o<512 -> mode1 path into Yt (Kt); o>=512 -> Vt f16 [b*512+o'][640], cols>=625 zero
__global__ __launch_bounds__(256) void k_gemm_mfma(
    const f16* __restrict__ W, const f16* __restrict__ Xt,
    float* __restrict__ Yf, f16* __restrict__ Yt, f16* __restrict__ Vt,
    const int Md, const int Nd, const int NtRows, const int mode, const float oscale,
    fp __restrict__ bias,
    fp __restrict__ bn_g, fp __restrict__ bn_b, fp __restrict__ bn_m, fp __restrict__ bn_v)
{
    __shared__ f16 sA[128 * 80];   // [m][k], stride 80 (160B rows: 16B-aligned, bank-balanced)
    __shared__ f16 sB[128 * 80];   // [n][k]
    const int b  = blockIdx.z;
    const int m0 = blockIdx.y * 128, n0 = blockIdx.x * 128;
    const int t = threadIdx.x;
    const int lane = t & 63, w = t >> 6;
    const int lm = lane & 15, q = lane >> 4;
    const int wm = w >> 1, wn = w & 1;
    const f16* Xb = Xt + (size_t)b * Nd * 512;

    f32x4 acc[4][4];
    #pragma unroll
    for (int i = 0; i < 4; i++)
        #pragma unroll
        for (int j = 0; j < 4; j++)
            #pragma unroll
            for (int r = 0; r < 4; r++) acc[i][j][r] = 0.f;

    for (int k0 = 0; k0 < 512; k0 += 64) {
        {   // stage A (W f16), 128 rows x 64 k; m0+r < Md always (grid exact)
            int r = t >> 1, hh = (t & 1) * 32;
            const f16* wr = W + (size_t)(m0 + r) * 512 + k0 + hh;
            f16* dst = &sA[r * 80 + hh];
            #pragma unroll
            for (int i = 0; i < 4; i++)
                *(f16x8*)&dst[i * 8] = *(const f16x8*)&wr[i * 8];
        }
        {   // stage B (Xt f16), 128 n-rows x 64 k
            int r = t >> 1, hh = (t & 1) * 32;
            bool ok = (n0 + r) < Nd;
            const f16* xr = Xb + (size_t)(n0 + r) * 512 + k0 + hh;
            f16* dst = &sB[r * 80 + hh];
            #pragma unroll
            for (int i = 0; i < 4; i++) {
                f16x8 v;
                if (ok) {
                    v = *(const f16x8*)&xr[i * 8];
                } else {
                    for (int z = 0; z < 8; z++) v[z] = (f16)0.f;
                }
                *(f16x8*)&dst[i * 8] = v;
            }
        }
        __syncthreads();
        #pragma unroll
        for (int ks = 0; ks < 2; ks++) {
            f16x8 af[4], bf[4];
            #pragma unroll
            for (int i = 0; i < 4; i++)
                af[i] = *(const f16x8*)&sA[(wm * 64 + i * 16 + lm) * 80 + ks * 32 + q * 8];
            #pragma unroll
            for (int j = 0; j < 4; j++)
                bf[j] = *(const f16x8*)&sB[(wn * 64 + j * 16 + lm) * 80 + ks * 32 + q * 8];
            #pragma unroll
            for (int i = 0; i < 4; i++)
                #pragma unroll
                for (int j = 0; j < 4; j++)
                    acc[i][j] = __builtin_amdgcn_mfma_f32_16x16x32_f16(af[i], bf[j], acc[i][j], 0, 0, 0);
        }
        __syncthreads();
    }

    // epilogue: D layout col=lane&15 (n), row=q*4+reg (o)
    #pragma unroll
    for (int i = 0; i < 4; i++) {
        int ob = m0 + wm * 64 + i * 16 + q * 4;       // + reg
        float badd[4], bsc[4], bsh[4];
        #pragma unroll
        for (int r = 0; r < 4; r++) {
            int o = ob + r;
            badd[r] = bias ? bias[o] : 0.f;
            if (bn_g) { bsc[r] = bn_g[o] * rsqrtf(bn_v[o] + 1e-5f); bsh[r] = bn_b[o] - bn_m[o] * bsc[r]; }
            else      { bsc[r] = 1.f; bsh[r] = 0.f; }
        }
        #pragma unroll
        for (int j = 0; j < 4; j++) {
            int n = n0 + wn * 64 + j * 16 + lm;
            f32x4 a = acc[i][j];
            if (mode == 0) {
                if (n < Nd) {
                    #pragma unroll
                    for (int r = 0; r < 4; r++)
                        Yf[((size_t)b * Md + ob + r) * Nd + n] = (a[r] + badd[r]) * bsc[r] + bsh[r];
                }
            } else if (mode == 1 || (mode == 2 && ob < 512)) {
                // n < NtRows always (grid exact); rows >= 625 in mode 2 hold finite
                // bias-only values and are masked post-multiply in attention.
                f16x4 h;
                #pragma unroll
                for (int r = 0; r < 4; r++) h[r] = (f16)((a[r] + badd[r]) * oscale);
                int hh = ob >> 6, d0 = ob & 63;
                *(f16x4*)&Yt[((size_t)(b * 8 + hh) * NtRows + n) * 64 + d0] = h;
            } else { // mode 2, v-half -> Vt f16 [b*512 + o'][640], zero-pad cols >= 625
                #pragma unroll
                for (int r = 0; r < 4; r++) {
                    float val = (n < Nd) ? (a[r] + badd[r]) : 0.f;
                    Vt[((size_t)b * Cc + (ob + r - 512)) * 640 + n] = (f16)val;
                }
            }
        }
    }
}

// ---------------- MFMA flash attention ----------------
// Qt f16 [bh][2304][64] (pre-scaled by 0.125); Kt f16 [bh][640][64] (rows>=625 masked);
// Vt f16 [bh*64 + d][640] (cols>=625 zero)  ->  Obuf f32 [b][512][2304]
__global__ __launch_bounds__(256) void k_attn_mfma(
    const f16* __restrict__ Qt, const f16* __restrict__ Kt,
    const f16* __restrict__ Vt, float* __restrict__ Obuf)
{
    __shared__ f16 sK[64 * 80];       // [key][d]
    __shared__ f16 sV[64 * 80];       // [d][key]
    __shared__ f16 sP[4][16 * 80];    // per-wave [qrow][key]

    int bh = blockIdx.y;
    int n0 = blockIdx.x * 64;
    int t = threadIdx.x, w = t >> 6, lane = t & 63;
    int lm = lane & 15, q = lane >> 4;
    f16* sPw = &sP[w][0];

    // Q fragments (held in registers across all chunks)
    f16x8 qf[2];
    {
        const f16* qrow = Qt + ((size_t)bh * Nn + n0 + w * 16 + lm) * 64;
        qf[0] = *(const f16x8*)&qrow[q * 8];
        qf[1] = *(const f16x8*)&qrow[32 + q * 8];
    }

    f32x4 od[4];
    #pragma unroll
    for (int dt = 0; dt < 4; dt++)
        #pragma unroll
        for (int r = 0; r < 4; r++) od[dt][r] = 0.f;
    float mold[4], lold[4];
    #pragma unroll
    for (int r = 0; r < 4; r++) { mold[r] = -1e30f; lold[r] = 0.f; }

    int kr = t >> 2, kc = t & 3;
    const f16* kbase = Kt + (size_t)bh * 640 * 64;
    const f16* vbase = Vt + (size_t)bh * 64 * 640;

    for (int mc = 0; mc < 640; mc += 64) {
        {   // stage K [key][d] and V [d][key]
            const f16* ksrc = kbase + (size_t)(mc + kr) * 64;
            *(f16x8*)&sK[kr * 80 + kc * 8]      = *(const f16x8*)&ksrc[kc * 8];
            *(f16x8*)&sK[kr * 80 + 32 + kc * 8] = *(const f16x8*)&ksrc[32 + kc * 8];
            const f16* vsrc = vbase + (size_t)kr * 640 + mc;
            *(f16x8*)&sV[kr * 80 + kc * 8]      = *(const f16x8*)&vsrc[kc * 8];
            *(f16x8*)&sV[kr * 80 + 32 + kc * 8] = *(const f16x8*)&vsrc[32 + kc * 8];
        }
        __syncthreads();

        // scores S = Q K^T (scale pre-folded into Qt)
        f32x4 sc4[4];
        #pragma unroll
        for (int j = 0; j < 4; j++)
            #pragma unroll
            for (int r = 0; r < 4; r++) sc4[j][r] = 0.f;
        #pragma unroll
        for (int ks = 0; ks < 2; ks++) {
            #pragma unroll
            for (int j = 0; j < 4; j++) {
                f16x8 kf = *(const f16x8*)&sK[(j * 16 + lm) * 80 + ks * 32 + q * 8];
                sc4[j] = __builtin_amdgcn_mfma_f32_16x16x32_f16(qf[ks], kf, sc4[j], 0, 0, 0);
            }
        }

        // online softmax; row r = q*4+reg, cols j*16+lm. Mask only in the last chunk.
        const bool lastc = (mc >= 576);
        #pragma unroll
        for (int reg = 0; reg < 4; reg++) {
            float mx;
            if (lastc) {
                mx = -1e30f;
                #pragma unroll
                for (int j = 0; j < 4; j++) {
                    float s = sc4[j][reg];
                    if (576 + j * 16 + lm >= Ms) s = -1e30f;
                    sc4[j][reg] = s;
                    mx = fmaxf(mx, s);
                }
            } else {
                mx = fmaxf(fmaxf(sc4[0][reg], sc4[1][reg]),
                           fmaxf(sc4[2][reg], sc4[3][reg]));
            }
            #pragma unroll
            for (int off = 1; off < 16; off <<= 1) mx = fmaxf(mx, __shfl_xor(mx, off));
            float mnew = fmaxf(mold[reg], mx);
            float alpha = __expf(mold[reg] - mnew);
            float rs = 0.f;
            #pragma unroll
            for (int j = 0; j < 4; j++) {
                float p = __expf(sc4[j][reg] - mnew);
                sc4[j][reg] = p;
                rs += p;
            }
            #pragma unroll
            for (int off = 1; off < 16; off <<= 1) rs += __shfl_xor(rs, off);
            lold[reg] = lold[reg] * alpha + rs;
            mold[reg] = mnew;
            #pragma unroll
            for (int dt = 0; dt < 4; dt++) od[dt][reg] *= alpha;
            #pragma unroll
            for (int j = 0; j < 4; j++)
                sPw[(q * 4 + reg) * 80 + j * 16 + lm] = (f16)sc4[j][reg];
        }

        // O += P V : A=P[qrow][key], B=V^T[key][d] (sV holds [d][key])
        #pragma unroll
        for (int ks = 0; ks < 2; ks++) {
            f16x8 pa = *(const f16x8*)&sPw[lm * 80 + ks * 32 + q * 8];
            #pragma unroll
            for (int dt = 0; dt < 4; dt++) {
                f16x8 vf = *(const f16x8*)&sV[(dt * 16 + lm) * 80 + ks * 32 + q * 8];
                od[dt] = __builtin_amdgcn_mfma_f32_16x16x32_f16(pa, vf, od[dt], 0, 0, 0);
            }
        }
        __syncthreads();
    }

    float inv[4];
    #pragma unroll
    for (int r = 0; r < 4; r++) inv[r] = 1.f / lold[r];
    #pragma unroll
    for (int dt = 0; dt < 4; dt++) {
        f32x4 o;
        #pragma unroll
        for (int r = 0; r < 4; r++) o[r] = od[dt][r] * inv[r];
        size_t c = (size_t)bh * 64 + dt * 16 + lm;     // = b*512 + h*64 + d
        *(f32x4*)&Obuf[c * Nn + n0 + w * 16 + q * 4] = o;
    }
}

// ---------------- K8: 4x nearest upsample, float4 stores (coalesced, full lines) ----------
__global__ __launch_bounds__(256) void k_upsample(const float* __restrict__ O,
                                                  float* __restrict__ out) {
    size_t idx = (size_t)blockIdx.x * 256 + threadIdx.x;   // < B*C*192*48
    if (idx >= (size_t)Bsz * Cc * H0c * 48) return;
    int jg = (int)(idx % 48);
    int i  = (int)((idx / 48) % H0c);
    int bc = (int)(idx / ((size_t)48 * H0c));
    float s = O[(size_t)bc * Nn + (i >> 2) * Hh + jg];
    float4 pack = make_float4(s, s, s, s);
    *(float4*)(out + ((size_t)bc * H0c + i) * H0c + jg * 4) = pack;
}

extern "C" void kernel_launch(void* const* d_in, const int* in_sizes, int n_in,
                              void* d_out, int out_size, void* d_ws, size_t ws_size,
                              hipStream_t stream) {
    (void)in_sizes; (void)n_in; (void)out_size; (void)ws_size;
    fp x     = (fp)d_in[0];
    fp q_w   = (fp)d_in[1];
    fp q_b   = (fp)d_in[2];
    fp kv_w  = (fp)d_in[3];
    fp kv_b  = (fp)d_in[4];
    fp sr1_w = (fp)d_in[5];
    fp bn1_g = (fp)d_in[6];
    fp bn1_b = (fp)d_in[7];
    fp bn1_m = (fp)d_in[8];
    fp bn1_v = (fp)d_in[9];
    fp sr2_w = (fp)d_in[10];
    fp bn2_g = (fp)d_in[11];
    fp bn2_b = (fp)d_in[12];
    fp bn2_m = (fp)d_in[13];
    fp bn2_v = (fp)d_in[14];
    fp lc_w  = (fp)d_in[15];
    fp lc_b  = (fp)d_in[16];
    float* out = (float*)d_out;

    // workspace layout (f32 units), peak 12,552,192 f32 = 50.2 MB (<= proven 53.1 MB)
    // lifetimes: wh [k0..k6] | xds [k1..k3) | Obuf alias xds [k7..k8] | xt [k1..k2) |
    //            kv1t alias xt [k3..k4) | kv3t alias xt [k5..k6) | kv2 [k4..k5) |
    //            Kt,vt [k6..k7] | Qt [k2..k7]
    float* ws   = (float*)d_ws;
    float* xds  = ws;                          // [0, 4718592)
    float* Obuf = ws;                          // alias (xds dead before attn)
    float* kv2  = ws + 4718592;                // [4718592, 5998592)
    f16*   Kt   = (f16*)(ws + 5998592);        // 1,310,720 f16
    f16*   vt   = (f16*)(ws + 6653952);        // 1,310,720 f16
    f16*   xt   = (f16*)(ws + 7309312);        // 4,718,592 f16
    f16*   kv1t = xt;                          // alias (320,000 f16)
    f16*   kv3t = xt;                          // alias (320,000 f16)
    f16*   Qt   = (f16*)(ws + 9668608);        // 4,718,592 f16
    f16*   wh   = (f16*)(ws + 12027904);       // 1,048,576 f16

    // 0. weights -> f16 (once)
    k_cvtw<<<4096, 256, 0, stream>>>(q_w, sr2_w, kv_w, wh);
    // 1. downsample + transpose
    k_ds_t<<<dim3(72, 16, Bsz), 256, 0, stream>>>(x, xds, xt);
    // 2. q projection -> Qt (per-head f16, pre-scaled by 0.125: exact, exponent-only)
    k_gemm_mfma<<<dim3(18, 4, Bsz), 256, 0, stream>>>(wh, xt, nullptr, Qt, nullptr,
        Cc, Nn, Nn, 1, 0.125f, q_b, nullptr, nullptr, nullptr, nullptr);
    // 3. sr1 (2x2 dw s2 + BN + ReLU) + transpose
    k_sr1t<<<dim3(20, 16, Bsz), 256, 0, stream>>>(xds, sr1_w, bn1_g, bn1_b, bn1_m, bn1_v, kv1t);
    // 4. sr2 1x1 + BN -> kv2 f32
    k_gemm_mfma<<<dim3(5, 4, Bsz), 256, 0, stream>>>(wh + 262144, kv1t, kv2, nullptr, nullptr,
        Cc, Ms, 0, 0, 1.f, nullptr, bn2_g, bn2_b, bn2_m, bn2_v);
    // 5. lc (3x3 dw + bias + residual) + transpose
    k_lct<<<dim3(20, 16, Bsz), 256, 0, stream>>>(kv2, lc_w, lc_b, kv3t);
    // 6. kv projection -> Kt (per-head f16) + vt (f16, zero-padded cols)
    k_gemm_mfma<<<dim3(5, 8, Bsz), 256, 0, stream>>>(wh + 524288, kv3t, nullptr, Kt, vt,
        C2, Ms, 640, 2, 1.f, kv_b, nullptr, nullptr, nullptr, nullptr);
    // 7. attention -> Obuf (coalesced f32)
    k_attn_mfma<<<dim3(Nn / 64, Bsz * HNh), 256, 0, stream>>>(Qt, Kt, vt, Obuf);
    // 8. 4x upsample -> out (coalesced float4, full-line writes)
    k_upsample<<<(unsigned)((size_t)Bsz * Cc * H0c * 48 / 256), 256, 0, stream>>>(Obuf, out);
}